// Round 2
// baseline (166.745 us; speedup 1.0000x reference)
//
#include <hip/hip_runtime.h>

// out[n,a,b] = sigmoid(w2 . leaky(w1 . leaky(u'[n,a,:] - v[n,b,:]) + b1) + b2)
// u' = za.w0^T + b0, v = zb.w0^T  (precomputed f32; w1 packed bf16 frag-linear).
// Main kernel: block = (n, a-pair, b-half), 256 thr = 4 waves, M=64/wave
// (2 a-values x 32 b-rows), N=256. w1 (128KB bf16) staged once to LDS.

typedef float f32x16 __attribute__((ext_vector_type(16)));
typedef short bf16x8 __attribute__((ext_vector_type(8)));

static __device__ __forceinline__ unsigned short f32_to_bf16(float f) {
  unsigned int u = __float_as_uint(f);
  u += 0x7FFFu + ((u >> 16) & 1u);          // RTNE
  return (unsigned short)(u >> 16);
}

// ---------------------------------------------------------------------------
// Pack u' (f32, linear) and v (f32, MFMA-A-fragment-linear) in one kernel.
// grid 2048 (= n*256 + r), block 256 (thread = hidden channel h)
// ---------------------------------------------------------------------------
__global__ __launch_bounds__(256) void pack_uv_kernel(
    const float* __restrict__ za, const float* __restrict__ zb,
    const float* __restrict__ w0, const float* __restrict__ b0,
    float* __restrict__ upack, float* __restrict__ vpack) {
  int nr = blockIdx.x;              // n*256 + r
  int n = nr >> 8, r = nr & 255;
  __shared__ float arow[64], brow[64];
  int tid = threadIdx.x;
  if (tid < 64) arow[tid] = za[nr * 64 + tid];
  else if (tid < 128) brow[tid - 64] = zb[nr * 64 + (tid - 64)];
  __syncthreads();
  int h = tid;
  const float* w0r = w0 + h * 64;
  float ua = 0.f, vb = 0.f;
#pragma unroll
  for (int c = 0; c < 64; c += 4) {
    float4 w = *reinterpret_cast<const float4*>(w0r + c);
    ua += w.x * arow[c] + w.y * arow[c + 1] + w.z * arow[c + 2] + w.w * arow[c + 3];
    vb += w.x * brow[c] + w.y * brow[c + 1] + w.z * brow[c + 2] + w.w * brow[c + 3];
  }
  upack[nr * 256 + h] = ua + b0[h];
  // v fragment-linear: frag (n, bblock=r>>5, kiter=h>>4); lane = half*32 + (r&31)
  int bblock = r >> 5, lcol = r & 31;
  int kiter = h >> 4, rem = h & 15, half = rem >> 3, j = rem & 7;
  int lane = half * 32 + lcol;
  vpack[(((n * 8 + bblock) * 16 + kiter) * 64 + lane) * 8 + j] = vb;
}

// ---------------------------------------------------------------------------
// Pack w1 (256x256 row-major g,h) into B-fragment-linear bf16.
// frag (kiter=h>>4, cf=g>>5): lane = ((h&15)>>3)*32 + (g&31), j = h&7
// ---------------------------------------------------------------------------
__global__ __launch_bounds__(256) void pack_w1_kernel(
    const float* __restrict__ w1, unsigned short* __restrict__ w1pk) {
  int id = blockIdx.x * 256 + threadIdx.x;   // 0..65535
  int g = id >> 8, h = id & 255;
  float val = w1[id];
  int nb = g >> 5, lcol = g & 31;
  int kiter = h >> 4, rem = h & 15, half = rem >> 3, j = rem & 7;
  int lane = half * 32 + lcol;
  w1pk[((kiter * 8 + nb) * 64 + lane) * 8 + j] = f32_to_bf16(val);
}

// ---------------------------------------------------------------------------
// Main fused kernel. KCHUNK = kiters staged per LDS phase (16 => 128KB once,
// 8 => 64KB twice). 4 waves; wave handles b-rows [bblk*32, +32) for a0 AND a1.
// ---------------------------------------------------------------------------
template <int KCHUNK>
__global__ __launch_bounds__(256, 1) void fused_main(
    const float* __restrict__ upack, const float* __restrict__ vpack,
    const unsigned short* __restrict__ w1pk,
    const float* __restrict__ b1, const float* __restrict__ w2,
    const float* __restrict__ b2, float* __restrict__ out) {
  extern __shared__ __align__(16) unsigned char lds_raw[];
  int bid = blockIdx.x;             // n(3b) | apair(7b) | bhalf(1b)
  int n = bid >> 8;
  int apair = (bid >> 1) & 127;
  int bhalf = bid & 1;
  int a0 = apair * 2, a1 = a0 + 1;
  int tid = threadIdx.x;
  int wid = tid >> 6;
  int l = tid & 63;
  int l31 = l & 31, lh = l >> 5;
  int bblk = bhalf * 4 + wid;       // b-rows bblk*32 .. +32

  f32x16 acc0[8], acc1[8];
#pragma unroll
  for (int cf = 0; cf < 8; ++cf)
#pragma unroll
    for (int r = 0; r < 16; ++r) { acc0[cf][r] = 0.f; acc1[cf][r] = 0.f; }

  float b1v[8], w2v[8];
#pragma unroll
  for (int cf = 0; cf < 8; ++cf) {
    b1v[cf] = b1[cf * 32 + l31];
    w2v[cf] = w2[cf * 32 + l31];
  }

  const bf16x8* lfrag = reinterpret_cast<const bf16x8*>(lds_raw);
  const int nphase = 16 / KCHUNK;

  for (int ph = 0; ph < nphase; ++ph) {
    if (ph) __syncthreads();        // drain readers before restage
    // Stage KCHUNK*8KB of frag-linear w1 into LDS: chunks of 1KB (64 lanes x 16B)
    const unsigned char* gsrc =
        reinterpret_cast<const unsigned char*>(w1pk) + ph * KCHUNK * 8192;
#pragma unroll
    for (int it = 0; it < KCHUNK * 2; ++it) {
      int chunk = it * 4 + wid;
      __builtin_amdgcn_global_load_lds(
          (const __attribute__((address_space(1))) void*)(gsrc + chunk * 1024 + l * 16),
          (__attribute__((address_space(3))) void*)(lds_raw + chunk * 1024),
          16, 0, 0);
    }
    __syncthreads();

    const float* vb = vpack + ((size_t)((n * 8 + bblk) * 16 + ph * KCHUNK)) * 512 + l * 8;
    const float* u0b = upack + (n * 256 + a0) * 256 + ph * KCHUNK * 16 + lh * 8;
    const float* u1b = upack + (n * 256 + a1) * 256 + ph * KCHUNK * 16 + lh * 8;

#pragma unroll
    for (int kk = 0; kk < KCHUNK; ++kk) {
      float4 vA = *reinterpret_cast<const float4*>(vb + kk * 512);
      float4 vB = *reinterpret_cast<const float4*>(vb + kk * 512 + 4);
      float4 uA0 = *reinterpret_cast<const float4*>(u0b + kk * 16);
      float4 uA1 = *reinterpret_cast<const float4*>(u0b + kk * 16 + 4);
      float4 uB0 = *reinterpret_cast<const float4*>(u1b + kk * 16);
      float4 uB1 = *reinterpret_cast<const float4*>(u1b + kk * 16 + 4);
      float vv[8] = {vA.x, vA.y, vA.z, vA.w, vB.x, vB.y, vB.z, vB.w};
      float u0[8] = {uA0.x, uA0.y, uA0.z, uA0.w, uA1.x, uA1.y, uA1.z, uA1.w};
      float u1[8] = {uB0.x, uB0.y, uB0.z, uB0.w, uB1.x, uB1.y, uB1.z, uB1.w};
      bf16x8 af0, af1;
#pragma unroll
      for (int j = 0; j < 8; ++j) {
        float d0 = u0[j] - vv[j];
        d0 = fmaxf(d0, 0.01f * d0);
        af0[j] = (short)f32_to_bf16(d0);
        float d1 = u1[j] - vv[j];
        d1 = fmaxf(d1, 0.01f * d1);
        af1[j] = (short)f32_to_bf16(d1);
      }
#pragma unroll
      for (int cf = 0; cf < 8; ++cf) {
        bf16x8 bf = lfrag[(kk * 8 + cf) * 64 + l];
        acc0[cf] = __builtin_amdgcn_mfma_f32_32x32x16_bf16(af0, bf, acc0[cf], 0, 0, 0);
        acc1[cf] = __builtin_amdgcn_mfma_f32_32x32x16_bf16(af1, bf, acc1[cf], 0, 0, 0);
      }
    }
  }

  // Epilogue: hidden1 = leaky(acc + b1); p = hidden1 . w2; sigmoid
  float p0[16], p1[16];
#pragma unroll
  for (int r = 0; r < 16; ++r) { p0[r] = 0.f; p1[r] = 0.f; }
#pragma unroll
  for (int cf = 0; cf < 8; ++cf) {
#pragma unroll
    for (int r = 0; r < 16; ++r) {
      float h0 = acc0[cf][r] + b1v[cf];
      h0 = fmaxf(h0, 0.01f * h0);
      p0[r] += h0 * w2v[cf];
      float h1 = acc1[cf][r] + b1v[cf];
      h1 = fmaxf(h1, 0.01f * h1);
      p1[r] += h1 * w2v[cf];
    }
  }
#pragma unroll
  for (int r = 0; r < 16; ++r) {
#pragma unroll
    for (int m = 1; m < 32; m <<= 1) {
      p0[r] += __shfl_xor(p0[r], m, 64);
      p1[r] += __shfl_xor(p1[r], m, 64);
    }
  }
  float b2v = b2[0];
  if (l31 == 0) {
    int bcol = bhalf * 128 + wid * 32 + 4 * lh;   // b index base
#pragma unroll
    for (int r = 0; r < 16; ++r) {
      int row = (r & 3) + 8 * (r >> 2);           // C/D row map
      out[(n * 256 + a0) * 256 + bcol + row] = 1.f / (1.f + __expf(-(p0[r] + b2v)));
      out[(n * 256 + a1) * 256 + bcol + row] = 1.f / (1.f + __expf(-(p1[r] + b2v)));
    }
  }
}

extern "C" void kernel_launch(void* const* d_in, const int* in_sizes, int n_in,
                              void* d_out, int out_size, void* d_ws, size_t ws_size,
                              hipStream_t stream) {
  const float* za = (const float*)d_in[0];
  const float* zb = (const float*)d_in[1];
  const float* w0 = (const float*)d_in[2];
  const float* b0 = (const float*)d_in[3];
  const float* w1 = (const float*)d_in[4];
  const float* b1 = (const float*)d_in[5];
  const float* w2 = (const float*)d_in[6];
  const float* b2 = (const float*)d_in[7];
  float* out = (float*)d_out;

  char* ws = (char*)d_ws;
  float* upack = (float*)ws;                              // 2 MB
  float* vpack = (float*)(ws + (2u << 20));               // 2 MB
  unsigned short* w1pk = (unsigned short*)(ws + (4u << 20)); // 128 KB

  pack_uv_kernel<<<2048, 256, 0, stream>>>(za, zb, w0, b0, upack, vpack);
  pack_w1_kernel<<<256, 256, 0, stream>>>(w1, w1pk);

  hipError_t e = hipFuncSetAttribute(
      reinterpret_cast<const void*>(fused_main<16>),
      hipFuncAttributeMaxDynamicSharedMemorySize, 131072);
  if (e == hipSuccess) {
    fused_main<16><<<2048, 256, 131072, stream>>>(upack, vpack, w1pk, b1, w2, b2, out);
  } else {
    fused_main<8><<<2048, 256, 65536, stream>>>(upack, vpack, w1pk, b1, w2, b2, out);
  }
}